// Round 3
// baseline (215.455 us; speedup 1.0000x reference)
//
#include <hip/hip_runtime.h>
#include <hip/hip_bf16.h>

// MultiHeadSelfAttention: B=2, S=2048, D=1024, H=16, DK=64
// R3: (a) QKV epilogue stores V coalesced [bh][s][dk]; new LDS transpose kernel
//     makes Vt (the R2 per-lane 4KB-stride scatter was ~4.2M L2 write requests).
//     (b) attn: V-frags hoisted out of m-loop; P stored fp32 row-major stride 68
//     (dword-pair writes + b128 reads, cvt on read); K/V staging via
//     global_load_lds w/ XOR swizzle (unpadded stride-64 LDS).

using bf16 = __hip_bfloat16;
typedef __attribute__((ext_vector_type(8))) short bf16x8;   // 8 bf16 = 4 VGPRs
typedef __attribute__((ext_vector_type(4))) float f32x4;

#define QSCALE 0.18033688011112042f   // (1/sqrt(64)) * log2(e)

static __device__ __forceinline__ f32x4 mfma_bf16(bf16x8 a, bf16x8 b, f32x4 c) {
    return __builtin_amdgcn_mfma_f32_16x16x32_bf16(a, b, c, 0, 0, 0);
}

// async global -> LDS, 16 bytes per lane; lane l deposits at ldsbase + 16*l.
static __device__ __forceinline__ void gld_lds16(const void* g, void* s) {
    __builtin_amdgcn_global_load_lds(
        (const __attribute__((address_space(1))) unsigned int*)g,
        (__attribute__((address_space(3))) unsigned int*)s,
        16, 0, 0);
}

static __device__ __forceinline__ short f2s(float f) {
    bf16 h = __float2bfloat16(f);
    return *reinterpret_cast<short*>(&h);
}
static __device__ __forceinline__ bf16x8 pack8(float4 a, float4 b) {
    bf16x8 r;
    r[0] = f2s(a.x); r[1] = f2s(a.y); r[2] = f2s(a.z); r[3] = f2s(a.w);
    r[4] = f2s(b.x); r[5] = f2s(b.y); r[6] = f2s(b.z); r[7] = f2s(b.w);
    return r;
}

// ---------------- cast x (fp32 -> bf16), vectorized ----------------
__global__ void cast_bf16_kernel(const float* __restrict__ in, bf16* __restrict__ out, int n4) {
    int i = blockIdx.x * blockDim.x + threadIdx.x;
    if (i >= n4) return;
    float4 f = reinterpret_cast<const float4*>(in)[i];
    out[4*i+0] = __float2bfloat16(f.x);
    out[4*i+1] = __float2bfloat16(f.y);
    out[4*i+2] = __float2bfloat16(f.z);
    out[4*i+3] = __float2bfloat16(f.w);
}

// ---------------- transpose + cast: in fp32 [R][C] -> out bf16 [C][R] ----------------
__global__ void transpose_cast_kernel(const float* __restrict__ in, bf16* __restrict__ out,
                                      int R, int C) {
    __shared__ float tile[32][33];
    int c0 = blockIdx.x * 32, r0 = blockIdx.y * 32;
    int x = threadIdx.x, y = threadIdx.y;   // block (32,8)
#pragma unroll
    for (int i = 0; i < 32; i += 8) tile[y + i][x] = in[(size_t)(r0 + y + i) * C + c0 + x];
    __syncthreads();
#pragma unroll
    for (int i = 0; i < 32; i += 8)
        out[(size_t)(c0 + y + i) * R + r0 + x] = __float2bfloat16(tile[x][y + i]);
}

// ---------------- transpose V: [bh][2048][64] -> [bh][64][2048] (bf16) ----------------
__global__ void transpose_v_kernel(const bf16* __restrict__ in, bf16* __restrict__ out) {
    __shared__ bf16 t[64][72];
    const int bh = blockIdx.y, s0 = blockIdx.x * 64;
    const int r = threadIdx.x >> 2, c16 = (threadIdx.x & 3) * 16;
    const uint4* src = (const uint4*)(in + ((size_t)bh * 2048 + s0 + r) * 64 + c16);
    uint4 a = src[0], b = src[1];
    *(uint4*)&t[r][c16] = a;
    *(uint4*)&t[r][c16 + 8] = b;
    __syncthreads();
    bf16 tmp[16];
#pragma unroll
    for (int i = 0; i < 16; ++i) tmp[i] = t[c16 + i][r];
    uint4* dst = (uint4*)(out + ((size_t)bh * 64 + r) * 2048 + s0 + c16);
    dst[0] = ((uint4*)tmp)[0];
    dst[1] = ((uint4*)tmp)[1];
}

// ---------------- GEMM: C[M,N] = A[M,K] @ Bt[N,K]^T  (bf16 in, fp32 acc) ----------------
template <int EPI>
__global__ __launch_bounds__(256, 2)
void gemm_bt_kernel(const bf16* __restrict__ A, const bf16* __restrict__ Bt,
                    int M, int N, int K,
                    const float* __restrict__ bias, const float* __restrict__ gamma,
                    bf16* __restrict__ Qout, bf16* __restrict__ Kout, bf16* __restrict__ Vout,
                    float* __restrict__ Cout) {
    __shared__ __align__(16) bf16 As[128 * 64];
    __shared__ __align__(16) bf16 Bs[128 * 64];

    const int tid  = threadIdx.x;
    const int wave = tid >> 6, lane = tid & 63;
    const int quad = lane >> 4, l16 = lane & 15;
    const int wr = wave >> 1, wc = wave & 1;
    const int bm = blockIdx.y, bn = blockIdx.x;

    f32x4 acc[4][4] = {};

    const int crow = lane >> 3;
    const int sblk = (lane & 7) ^ (crow & 7);
    const bf16* gA[4]; const bf16* gB[4]; bf16* lA[4]; bf16* lB[4];
#pragma unroll
    for (int c = 0; c < 4; ++c) {
        int rt = wave * 32 + c * 8 + crow;
        gA[c] = A  + (size_t)(bm * 128 + rt) * K + sblk * 8;
        gB[c] = Bt + (size_t)(bn * 128 + rt) * K + sblk * 8;
        lA[c] = As + (wave * 4 + c) * 512 + lane * 8;
        lB[c] = Bs + (wave * 4 + c) * 512 + lane * 8;
    }
    const int xr = l16 & 7;

    for (int k0 = 0; k0 < K; k0 += 64) {
#pragma unroll
        for (int c = 0; c < 4; ++c) gld_lds16(gA[c] + k0, lA[c]);
#pragma unroll
        for (int c = 0; c < 4; ++c) gld_lds16(gB[c] + k0, lB[c]);
        __syncthreads();
#pragma unroll
        for (int ks = 0; ks < 2; ++ks) {
            bf16x8 af[4], bfr[4];
#pragma unroll
            for (int mi = 0; mi < 4; ++mi)
                af[mi] = *(const bf16x8*)(As + (wr * 64 + mi * 16 + l16) * 64 + ((4 * ks + quad) ^ xr) * 8);
#pragma unroll
            for (int ni = 0; ni < 4; ++ni)
                bfr[ni] = *(const bf16x8*)(Bs + (wc * 64 + ni * 16 + l16) * 64 + ((4 * ks + quad) ^ xr) * 8);
#pragma unroll
            for (int mi = 0; mi < 4; ++mi)
#pragma unroll
                for (int ni = 0; ni < 4; ++ni)
                    acc[mi][ni] = mfma_bf16(af[mi], bfr[ni], acc[mi][ni]);
        }
        __syncthreads();
    }

#pragma unroll
    for (int mi = 0; mi < 4; ++mi) {
#pragma unroll
        for (int ni = 0; ni < 4; ++ni) {
#pragma unroll
            for (int r = 0; r < 4; ++r) {
                int row = bm * 128 + wr * 64 + mi * 16 + quad * 4 + r;
                int col = bn * 128 + wc * 64 + ni * 16 + l16;
                float v = acc[mi][ni][r];
                if (EPI == 0) {
                    v += bias[col];
                    int h = col / 192;
                    int rr = col - h * 192;
                    int which = rr >> 6, dk = rr & 63;
                    int b = row >> 11, s = row & 2047;   // S = 2048
                    size_t bh = (size_t)b * 16 + h;
                    if (which == 0) {
                        Qout[(bh * 2048 + s) * 64 + dk] = __float2bfloat16(v * QSCALE);
                    } else if (which == 1) {
                        Kout[(bh * 2048 + s) * 64 + dk] = __float2bfloat16(v);
                    } else {
                        // coalesced: same layout as K; separate kernel transposes
                        Vout[(bh * 2048 + s) * 64 + dk] = __float2bfloat16(v);
                    }
                } else {
                    float o = (gamma[col] + 1.0f) * (v + bias[col]);
                    Cout[(size_t)row * N + col] = o;
                }
            }
        }
    }
}

// ---------------- flash attention, static-max softmax ----------------
// grid: (S/128, B*H). block 256 = 4 waves; wave w owns q rows [q0+32w, q0+32w+32).
// P stored fp32 row-major (stride 68 dw): scalar dword writes pair-merge into
// ds_write2_b32; reads are aligned b128; cvt->bf16 on read.
__global__ __launch_bounds__(256, 2)
void attn_kernel(const bf16* __restrict__ Qb, const bf16* __restrict__ Kb,
                 const bf16* __restrict__ Vt, const int* __restrict__ mask,
                 bf16* __restrict__ Aout) {
    __shared__ __align__(16) bf16 Ks[64 * 64];      // [kpos][dk], XOR-swizzled blocks
    __shared__ __align__(16) bf16 Vs[64 * 64];      // [dk][kpos], XOR-swizzled blocks
    __shared__ __align__(16) float Psf[4][32 * 68]; // per-wave P fp32 [qrow][kpos]
    __shared__ float Biass[64];

    const int bh = blockIdx.y;
    const int b = bh >> 4, h = bh & 15;
    const int q0 = blockIdx.x * 128;
    const int tid = threadIdx.x;
    const int wave = tid >> 6, lane = tid & 63;
    const int quad = lane >> 4, l16 = lane & 15;
    const int xr = l16 & 7;

    // Q A-fragments (constant over k loop)
    bf16x8 aq[2][2];
#pragma unroll
    for (int m = 0; m < 2; ++m) {
        const bf16* qp = Qb + ((size_t)bh * 2048 + q0 + wave * 32 + m * 16 + l16) * 64;
        aq[m][0] = *(const bf16x8*)(qp + quad * 8);
        aq[m][1] = *(const bf16x8*)(qp + 32 + quad * 8);
    }

    bf16x8 ones;
#pragma unroll
    for (int j = 0; j < 8; ++j) ones[j] = (short)0x3F80;   // bf16 1.0

    f32x4 O[2][4] = {};
    f32x4 Lacc[2] = {};

    // DMA staging: chunk ch = wave*2+c covers rows [ch*8, ch*8+8); lane l ->
    // row ch*8 + (l>>3), phys block l&7 holds source block (l&7)^(l>>3&7).
    const int crow = lane >> 3;
    const int sblk = (lane & 7) ^ (crow & 7);
    const bf16* gK[2]; const bf16* gV[2]; bf16* lK[2]; bf16* lV[2];
#pragma unroll
    for (int c = 0; c < 2; ++c) {
        int ch = wave * 2 + c;
        gK[c] = Kb + ((size_t)bh * 2048 + ch * 8 + crow) * 64 + sblk * 8;
        gV[c] = Vt + ((size_t)bh * 64 + ch * 8 + crow) * 2048 + sblk * 8;
        lK[c] = Ks + ch * 512 + lane * 8;
        lV[c] = Vs + ch * 512 + lane * 8;
    }
    float* myP = &Psf[wave][0];

    int mreg = (tid < 64) ? mask[b * 2048 + tid] : 0;

    for (int kt = 0; kt < 32; ++kt) {
#pragma unroll
        for (int c = 0; c < 2; ++c) {
            gld_lds16(gK[c] + (size_t)kt * 4096, lK[c]);
            gld_lds16(gV[c] + kt * 64, lV[c]);
        }
        if (tid < 64) Biass[tid] = mreg ? -24.0f : -1e30f;
        __syncthreads();   // drains DMA (vmcnt) + LDS writes

        if (kt + 1 < 32 && tid < 64) mreg = mask[b * 2048 + (kt + 1) * 64 + tid];

        float bv4[4];
        bf16x8 bk[4][2];
#pragma unroll
        for (int nt = 0; nt < 4; ++nt) {
            bv4[nt] = Biass[nt * 16 + l16];
            const bf16* kp = Ks + (nt * 16 + l16) * 64;
            bk[nt][0] = *(const bf16x8*)(kp + ((quad) ^ xr) * 8);
            bk[nt][1] = *(const bf16x8*)(kp + ((quad + 4) ^ xr) * 8);
        }

        // S = Q K^T, p = exp2(c + bias), write P (fp32, dword-pair merges)
#pragma unroll
        for (int m = 0; m < 2; ++m) {
#pragma unroll
            for (int nt = 0; nt < 4; ++nt) {
                f32x4 c = {0.f, 0.f, 0.f, 0.f};
                c = mfma_bf16(aq[m][0], bk[nt][0], c);
                c = mfma_bf16(aq[m][1], bk[nt][1], c);
                float* pw = myP + (m * 16 + quad * 4) * 68 + nt * 16 + l16;
#pragma unroll
                for (int r = 0; r < 4; ++r)
                    pw[r * 68] = __builtin_amdgcn_exp2f(c[r] + bv4[nt]);
            }
        }

        // V fragments hoisted (shared across both m-groups)
        bf16x8 bv[2][4];
#pragma unroll
        for (int ks = 0; ks < 2; ++ks)
#pragma unroll
            for (int nt = 0; nt < 4; ++nt)
                bv[ks][nt] = *(const bf16x8*)(Vs + (nt * 16 + l16) * 64 + ((quad + 4 * ks) ^ xr) * 8);

        // O += P V ; l += P @ ones
#pragma unroll
        for (int m = 0; m < 2; ++m) {
#pragma unroll
            for (int ks = 0; ks < 2; ++ks) {
                const float4* pp = (const float4*)(myP + (m * 16 + l16) * 68 + ks * 32 + quad * 8);
                float4 p0 = pp[0], p1 = pp[1];
                bf16x8 ap = pack8(p0, p1);
                Lacc[m] = mfma_bf16(ap, ones, Lacc[m]);
#pragma unroll
                for (int nt = 0; nt < 4; ++nt)
                    O[m][nt] = mfma_bf16(ap, bv[ks][nt], O[m][nt]);
            }
        }
        __syncthreads();
    }

    // epilogue: O / l
#pragma unroll
    for (int m = 0; m < 2; ++m) {
        float inv[4];
#pragma unroll
        for (int r = 0; r < 4; ++r) inv[r] = __builtin_amdgcn_rcpf(Lacc[m][r]);
#pragma unroll
        for (int nt = 0; nt < 4; ++nt) {
#pragma unroll
            for (int r = 0; r < 4; ++r) {
                int row = q0 + wave * 32 + m * 16 + quad * 4 + r;
                Aout[((size_t)b * 2048 + row) * 1024 + h * 64 + nt * 16 + l16] =
                    __float2bfloat16(O[m][nt][r] * inv[r]);
            }
        }
    }
}

// ---------------- launcher ----------------
extern "C" void kernel_launch(void* const* d_in, const int* in_sizes, int n_in,
                              void* d_out, int out_size, void* d_ws, size_t ws_size,
                              hipStream_t stream) {
    const float* x     = (const float*)d_in[0];
    const float* gamma = (const float*)d_in[1];
    const int*   mask  = (const int*)d_in[2];
    const float* wqkv  = (const float*)d_in[3];
    const float* bqkv  = (const float*)d_in[4];
    const float* wo    = (const float*)d_in[5];
    const float* bo    = (const float*)d_in[6];
    float* out = (float*)d_out;

    char* ws = (char*)d_ws;
    const size_t MB = 1u << 20;
    bf16* xb    = (bf16*)(ws);            //  8 MB: x cast to bf16      [4096][1024]
    bf16* wqkvT = (bf16*)(ws + 8 * MB);   //  6 MB: W_qkv^T bf16        [3072][1024]
    bf16* woT   = (bf16*)(ws + 14 * MB);  //  2 MB: W_o^T bf16          [1024][1024]
    bf16* Qb    = (bf16*)(ws + 16 * MB);  //  8 MB: Q per head (scaled) [bh][s][dk]
    bf16* Kb    = (bf16*)(ws + 24 * MB);  //  8 MB: K per head          [bh][s][dk]
    bf16* Vt    = (bf16*)(ws + 32 * MB);  //  8 MB: V^T per head        [bh][dk][s]
    bf16* Vtmp  = (bf16*)(ws + 40 * MB);  //  8 MB: V coalesced         [bh][s][dk] (dead after transpose)
    bf16* attn  = (bf16*)(ws + 40 * MB);  //  8 MB: attention out (reuses Vtmp slot)

    cast_bf16_kernel<<<4096, 256, 0, stream>>>(x, xb, 4194304 / 4);
    transpose_cast_kernel<<<dim3(96, 32), dim3(32, 8), 0, stream>>>(wqkv, wqkvT, 1024, 3072);
    transpose_cast_kernel<<<dim3(32, 32), dim3(32, 8), 0, stream>>>(wo, woT, 1024, 1024);

    // QKV GEMM: [4096,1024] x [1024,3072]
    gemm_bt_kernel<0><<<dim3(24, 32), 256, 0, stream>>>(
        xb, wqkvT, 4096, 3072, 1024, bqkv, nullptr, Qb, Kb, Vtmp, nullptr);

    // V transpose: [bh][s][dk] -> [bh][dk][s]
    transpose_v_kernel<<<dim3(32, 32), 256, 0, stream>>>(Vtmp, Vt);

    // attention: grid (S/128, B*H)
    attn_kernel<<<dim3(16, 32), 256, 0, stream>>>(Qb, Kb, Vt, mask, attn);

    // out GEMM: [4096,1024] x [1024,1024], fused bias + (gamma+1)
    gemm_bt_kernel<1><<<dim3(8, 32), 256, 0, stream>>>(
        attn, woT, 4096, 1024, 1024, bo, gamma, nullptr, nullptr, nullptr, out);
}

// Round 4
// 209.446 us; speedup vs baseline: 1.0287x; 1.0287x over previous
//
#include <hip/hip_runtime.h>
#include <hip/hip_bf16.h>

// MultiHeadSelfAttention: B=2, S=2048, D=1024, H=16, DK=64
// R4: attn computes S^T = K*Q^T (operand swap) so P lands pre-aligned for the
//     PV A-operand via dual-16k-slice packing in one 16x16x32 MFMA. P never
//     touches LDS (R2/R3 spent ~40% of LDS bandwidth on the P round-trip).
//     K/V staging = R2 reg-prefetch (R3's gld_lds+sync had no latency hiding).
//     V LDS stride 76 for uniform b64 bank depth. GEMM path unchanged from R3.

using bf16 = __hip_bfloat16;
typedef __attribute__((ext_vector_type(8))) short bf16x8;   // 8 bf16 = 4 VGPRs
typedef __attribute__((ext_vector_type(4))) short bf16x4;   // 4 bf16 = 2 VGPRs
typedef __attribute__((ext_vector_type(4))) float f32x4;

#define QSCALE 0.18033688011112042f   // (1/sqrt(64)) * log2(e)

static __device__ __forceinline__ f32x4 mfma_bf16(bf16x8 a, bf16x8 b, f32x4 c) {
    return __builtin_amdgcn_mfma_f32_16x16x32_bf16(a, b, c, 0, 0, 0);
}

// async global -> LDS, 16 bytes per lane (GEMM staging)
static __device__ __forceinline__ void gld_lds16(const void* g, void* s) {
    __builtin_amdgcn_global_load_lds(
        (const __attribute__((address_space(1))) unsigned int*)g,
        (__attribute__((address_space(3))) unsigned int*)s,
        16, 0, 0);
}

static __device__ __forceinline__ short f2s(float f) {
    bf16 h = __float2bfloat16(f);
    return *reinterpret_cast<short*>(&h);
}

// ---------------- cast x (fp32 -> bf16), vectorized ----------------
__global__ void cast_bf16_kernel(const float* __restrict__ in, bf16* __restrict__ out, int n4) {
    int i = blockIdx.x * blockDim.x + threadIdx.x;
    if (i >= n4) return;
    float4 f = reinterpret_cast<const float4*>(in)[i];
    out[4*i+0] = __float2bfloat16(f.x);
    out[4*i+1] = __float2bfloat16(f.y);
    out[4*i+2] = __float2bfloat16(f.z);
    out[4*i+3] = __float2bfloat16(f.w);
}

// ---------------- transpose + cast: in fp32 [R][C] -> out bf16 [C][R] ----------------
__global__ void transpose_cast_kernel(const float* __restrict__ in, bf16* __restrict__ out,
                                      int R, int C) {
    __shared__ float tile[32][33];
    int c0 = blockIdx.x * 32, r0 = blockIdx.y * 32;
    int x = threadIdx.x, y = threadIdx.y;   // block (32,8)
#pragma unroll
    for (int i = 0; i < 32; i += 8) tile[y + i][x] = in[(size_t)(r0 + y + i) * C + c0 + x];
    __syncthreads();
#pragma unroll
    for (int i = 0; i < 32; i += 8)
        out[(size_t)(c0 + y + i) * R + r0 + x] = __float2bfloat16(tile[x][y + i]);
}

// ---------------- transpose V: [bh][2048][64] -> [bh][64][2048] (bf16) ----------------
__global__ void transpose_v_kernel(const bf16* __restrict__ in, bf16* __restrict__ out) {
    __shared__ bf16 t[64][72];
    const int bh = blockIdx.y, s0 = blockIdx.x * 64;
    const int r = threadIdx.x >> 2, c16 = (threadIdx.x & 3) * 16;
    const uint4* src = (const uint4*)(in + ((size_t)bh * 2048 + s0 + r) * 64 + c16);
    uint4 a = src[0], b = src[1];
    *(uint4*)&t[r][c16] = a;
    *(uint4*)&t[r][c16 + 8] = b;
    __syncthreads();
    bf16 tmp[16];
#pragma unroll
    for (int i = 0; i < 16; ++i) tmp[i] = t[c16 + i][r];
    uint4* dst = (uint4*)(out + ((size_t)bh * 64 + r) * 2048 + s0 + c16);
    dst[0] = ((uint4*)tmp)[0];
    dst[1] = ((uint4*)tmp)[1];
}

// ---------------- GEMM: C[M,N] = A[M,K] @ Bt[N,K]^T  (bf16 in, fp32 acc) ----------------
template <int EPI>
__global__ __launch_bounds__(256, 2)
void gemm_bt_kernel(const bf16* __restrict__ A, const bf16* __restrict__ Bt,
                    int M, int N, int K,
                    const float* __restrict__ bias, const float* __restrict__ gamma,
                    bf16* __restrict__ Qout, bf16* __restrict__ Kout, bf16* __restrict__ Vout,
                    float* __restrict__ Cout) {
    __shared__ __align__(16) bf16 As[128 * 64];
    __shared__ __align__(16) bf16 Bs[128 * 64];

    const int tid  = threadIdx.x;
    const int wave = tid >> 6, lane = tid & 63;
    const int quad = lane >> 4, l16 = lane & 15;
    const int wr = wave >> 1, wc = wave & 1;
    const int bm = blockIdx.y, bn = blockIdx.x;

    f32x4 acc[4][4] = {};

    const int crow = lane >> 3;
    const int sblk = (lane & 7) ^ (crow & 7);
    const bf16* gA[4]; const bf16* gB[4]; bf16* lA[4]; bf16* lB[4];
#pragma unroll
    for (int c = 0; c < 4; ++c) {
        int rt = wave * 32 + c * 8 + crow;
        gA[c] = A  + (size_t)(bm * 128 + rt) * K + sblk * 8;
        gB[c] = Bt + (size_t)(bn * 128 + rt) * K + sblk * 8;
        lA[c] = As + (wave * 4 + c) * 512 + lane * 8;
        lB[c] = Bs + (wave * 4 + c) * 512 + lane * 8;
    }
    const int xr = l16 & 7;

    for (int k0 = 0; k0 < K; k0 += 64) {
#pragma unroll
        for (int c = 0; c < 4; ++c) gld_lds16(gA[c] + k0, lA[c]);
#pragma unroll
        for (int c = 0; c < 4; ++c) gld_lds16(gB[c] + k0, lB[c]);
        __syncthreads();
#pragma unroll
        for (int ks = 0; ks < 2; ++ks) {
            bf16x8 af[4], bfr[4];
#pragma unroll
            for (int mi = 0; mi < 4; ++mi)
                af[mi] = *(const bf16x8*)(As + (wr * 64 + mi * 16 + l16) * 64 + ((4 * ks + quad) ^ xr) * 8);
#pragma unroll
            for (int ni = 0; ni < 4; ++ni)
                bfr[ni] = *(const bf16x8*)(Bs + (wc * 64 + ni * 16 + l16) * 64 + ((4 * ks + quad) ^ xr) * 8);
#pragma unroll
            for (int mi = 0; mi < 4; ++mi)
#pragma unroll
                for (int ni = 0; ni < 4; ++ni)
                    acc[mi][ni] = mfma_bf16(af[mi], bfr[ni], acc[mi][ni]);
        }
        __syncthreads();
    }

#pragma unroll
    for (int mi = 0; mi < 4; ++mi) {
#pragma unroll
        for (int ni = 0; ni < 4; ++ni) {
#pragma unroll
            for (int r = 0; r < 4; ++r) {
                int row = bm * 128 + wr * 64 + mi * 16 + quad * 4 + r;
                int col = bn * 128 + wc * 64 + ni * 16 + l16;
                float v = acc[mi][ni][r];
                if (EPI == 0) {
                    v += bias[col];
                    int h = col / 192;
                    int rr = col - h * 192;
                    int which = rr >> 6, dk = rr & 63;
                    int b = row >> 11, s = row & 2047;   // S = 2048
                    size_t bh = (size_t)b * 16 + h;
                    if (which == 0) {
                        Qout[(bh * 2048 + s) * 64 + dk] = __float2bfloat16(v * QSCALE);
                    } else if (which == 1) {
                        Kout[(bh * 2048 + s) * 64 + dk] = __float2bfloat16(v);
                    } else {
                        Vout[(bh * 2048 + s) * 64 + dk] = __float2bfloat16(v);
                    }
                } else {
                    float o = (gamma[col] + 1.0f) * (v + bias[col]);
                    Cout[(size_t)row * N + col] = o;
                }
            }
        }
    }
}

// ---------------- flash attention, S^T orientation, no P round-trip ----------------
// grid: (S/128, B*H). block 256 = 4 waves; wave w owns q rows [q0+32w, q0+32w+32).
// S^T = K*Q^T: lane (quad,l16) holds S[q=l16][kpos=16*kt4+quad*4+r] -> exactly the
// dual-slice A-operand packing for PV 16x16x32 MFMA (j=0..3 <- kt4=2a, j=4..7 <- 2a+1,
// k16 = 4*quad+j). V B-frags = two b64 reads from V^T. l via ones-MFMA.
__global__ __launch_bounds__(256, 2)
void attn_kernel(const bf16* __restrict__ Qb, const bf16* __restrict__ Kb,
                 const bf16* __restrict__ Vt, const int* __restrict__ mask,
                 bf16* __restrict__ Aout) {
    __shared__ __align__(16) bf16 Ks[64 * 72];      // K tile [kpos][dk], stride 72
    __shared__ __align__(16) bf16 Vs[64 * 76];      // V^T tile [dk][kpos], stride 76
    __shared__ __align__(16) float Biass[64];

    const int bh = blockIdx.y;
    const int b = bh >> 4, h = bh & 15;
    const int q0 = blockIdx.x * 128;
    const int tid = threadIdx.x;
    const int wave = tid >> 6, lane = tid & 63;
    const int quad = lane >> 4, l16 = lane & 15;

    // Q fragments (B-operand now): B[n=l16=qrow][k=dk]
    bf16x8 aq[2][2];
#pragma unroll
    for (int m = 0; m < 2; ++m) {
        const bf16* qp = Qb + ((size_t)bh * 2048 + q0 + wave * 32 + m * 16 + l16) * 64;
        aq[m][0] = *(const bf16x8*)(qp + quad * 8);
        aq[m][1] = *(const bf16x8*)(qp + 32 + quad * 8);
    }

    bf16x8 ones;
#pragma unroll
    for (int j = 0; j < 8; ++j) ones[j] = (short)0x3F80;   // bf16 1.0

    f32x4 O[2][4] = {};
    f32x4 Lacc[2] = {};

    // staging: thread t -> row t>>2 (0..63), part t&3 -> 16 bf16 = 2x uint4
    const int srow = tid >> 2, spart = tid & 3;
    const bf16* gK = Kb + ((size_t)bh * 2048 + srow) * 64 + spart * 16;
    const bf16* gV = Vt + ((size_t)bh * 64 + srow) * 2048 + spart * 16;
    uint4* lK = (uint4*)(Ks + srow * 72 + spart * 16);
    uint4* lV = (uint4*)(Vs + srow * 76 + spart * 16);

    // prefetch tile 0
    uint4 kr0, kr1, vr0, vr1; int mreg = 1;
    {
        const uint4* nk = (const uint4*)gK;
        const uint4* nv = (const uint4*)gV;
        kr0 = nk[0]; kr1 = nk[1];
        vr0 = nv[0]; vr1 = nv[1];
        if (tid < 64) mreg = mask[b * 2048 + tid];
    }

    for (int kt = 0; kt < 32; ++kt) {
        lK[0] = kr0; lK[1] = kr1;
        lV[0] = vr0; lV[1] = vr1;
        if (tid < 64) Biass[tid] = mreg ? -24.0f : -1e30f;
        __syncthreads();

        if (kt + 1 < 32) {   // prefetch next tile into regs (overlaps compute)
            const uint4* nk = (const uint4*)(gK + (size_t)(kt + 1) * 64 * 64);
            const uint4* nv = (const uint4*)(gV + (kt + 1) * 64);
            kr0 = nk[0]; kr1 = nk[1];
            vr0 = nv[0]; vr1 = nv[1];
            if (tid < 64) mreg = mask[b * 2048 + (kt + 1) * 64 + tid];
        }

        // hoisted: bias rows, K A-frags, V B-frags
        f32x4 bias4[4];
        bf16x8 bk[4][2];
#pragma unroll
        for (int kt4 = 0; kt4 < 4; ++kt4) {
            bias4[kt4] = *(const f32x4*)(Biass + kt4 * 16 + quad * 4);
            const bf16* kp = Ks + (kt4 * 16 + l16) * 72 + quad * 8;
            bk[kt4][0] = *(const bf16x8*)kp;
            bk[kt4][1] = *(const bf16x8*)(kp + 32);
        }
        bf16x8 bv8[2][4];
#pragma unroll
        for (int a = 0; a < 2; ++a) {
#pragma unroll
            for (int nt = 0; nt < 4; ++nt) {
                const bf16* vp = Vs + (nt * 16 + l16) * 76 + a * 32 + quad * 4;
                bf16x4 lo = *(const bf16x4*)vp;          // kpos 32a+4q+0..3   (j=0..3)
                bf16x4 hi = *(const bf16x4*)(vp + 16);   // kpos 32a+16+4q+0..3 (j=4..7)
                bf16x8 f;
                f[0] = lo[0]; f[1] = lo[1]; f[2] = lo[2]; f[3] = lo[3];
                f[4] = hi[0]; f[5] = hi[1]; f[6] = hi[2]; f[7] = hi[3];
                bv8[a][nt] = f;
            }
        }

#pragma unroll
        for (int m = 0; m < 2; ++m) {
            // S^T tiles: D[kpos-slice][q] = K-frag x Q-frag
            f32x4 sv[4];
#pragma unroll
            for (int kt4 = 0; kt4 < 4; ++kt4) {
                f32x4 c = {0.f, 0.f, 0.f, 0.f};
                c = mfma_bf16(bk[kt4][0], aq[m][0], c);
                c = mfma_bf16(bk[kt4][1], aq[m][1], c);
                sv[kt4] = c;
            }
            // p = exp2(s + bias_k) ; pack dual-slice A-frags
            float p[4][4];
#pragma unroll
            for (int kt4 = 0; kt4 < 4; ++kt4)
#pragma unroll
                for (int r = 0; r < 4; ++r)
                    p[kt4][r] = __builtin_amdgcn_exp2f(sv[kt4][r] + bias4[kt4][r]);

#pragma unroll
            for (int a = 0; a < 2; ++a) {
                bf16x8 pa;
                pa[0] = f2s(p[2*a][0]);   pa[1] = f2s(p[2*a][1]);
                pa[2] = f2s(p[2*a][2]);   pa[3] = f2s(p[2*a][3]);
                pa[4] = f2s(p[2*a+1][0]); pa[5] = f2s(p[2*a+1][1]);
                pa[6] = f2s(p[2*a+1][2]); pa[7] = f2s(p[2*a+1][3]);
                Lacc[m] = mfma_bf16(pa, ones, Lacc[m]);
#pragma unroll
                for (int nt = 0; nt < 4; ++nt)
                    O[m][nt] = mfma_bf16(pa, bv8[a][nt], O[m][nt]);
            }
        }
        __syncthreads();
    }

    // epilogue: O / l  (O rows = quad*4+r, cols = nt*16+l16; Lacc same rows)
#pragma unroll
    for (int m = 0; m < 2; ++m) {
        float inv[4];
#pragma unroll
        for (int r = 0; r < 4; ++r) inv[r] = __builtin_amdgcn_rcpf(Lacc[m][r]);
#pragma unroll
        for (int nt = 0; nt < 4; ++nt) {
#pragma unroll
            for (int r = 0; r < 4; ++r) {
                int row = q0 + wave * 32 + m * 16 + quad * 4 + r;
                Aout[((size_t)b * 2048 + row) * 1024 + h * 64 + nt * 16 + l16] =
                    __float2bfloat16(O[m][nt][r] * inv[r]);
            }
        }
    }
}

// ---------------- launcher ----------------
extern "C" void kernel_launch(void* const* d_in, const int* in_sizes, int n_in,
                              void* d_out, int out_size, void* d_ws, size_t ws_size,
                              hipStream_t stream) {
    const float* x     = (const float*)d_in[0];
    const float* gamma = (const float*)d_in[1];
    const int*   mask  = (const int*)d_in[2];
    const float* wqkv  = (const float*)d_in[3];
    const float* bqkv  = (const float*)d_in[4];
    const float* wo    = (const float*)d_in[5];
    const float* bo    = (const float*)d_in[6];
    float* out = (float*)d_out;

    char* ws = (char*)d_ws;
    const size_t MB = 1u << 20;
    bf16* xb    = (bf16*)(ws);            //  8 MB: x cast to bf16      [4096][1024]
    bf16* wqkvT = (bf16*)(ws + 8 * MB);   //  6 MB: W_qkv^T bf16        [3072][1024]
    bf16* woT   = (bf16*)(ws + 14 * MB);  //  2 MB: W_o^T bf16          [1024][1024]
    bf16* Qb    = (bf16*)(ws + 16 * MB);  //  8 MB: Q per head (scaled) [bh][s][dk]
    bf16* Kb    = (bf16*)(ws + 24 * MB);  //  8 MB: K per head          [bh][s][dk]
    bf16* Vt    = (bf16*)(ws + 32 * MB);  //  8 MB: V^T per head        [bh][dk][s]
    bf16* Vtmp  = (bf16*)(ws + 40 * MB);  //  8 MB: V coalesced (dead after transpose)
    bf16* attn  = (bf16*)(ws + 40 * MB);  //  8 MB: attention out (reuses Vtmp slot)

    cast_bf16_kernel<<<4096, 256, 0, stream>>>(x, xb, 4194304 / 4);
    transpose_cast_kernel<<<dim3(96, 32), dim3(32, 8), 0, stream>>>(wqkv, wqkvT, 1024, 3072);
    transpose_cast_kernel<<<dim3(32, 32), dim3(32, 8), 0, stream>>>(wo, woT, 1024, 1024);

    // QKV GEMM: [4096,1024] x [1024,3072]
    gemm_bt_kernel<0><<<dim3(24, 32), 256, 0, stream>>>(
        xb, wqkvT, 4096, 3072, 1024, bqkv, nullptr, Qb, Kb, Vtmp, nullptr);

    // V transpose: [bh][s][dk] -> [bh][dk][s]
    transpose_v_kernel<<<dim3(32, 32), 256, 0, stream>>>(Vtmp, Vt);

    // attention: grid (S/128, B*H)
    attn_kernel<<<dim3(16, 32), 256, 0, stream>>>(Qb, Kb, Vt, mask, attn);

    // out GEMM: [4096,1024] x [1024,1024], fused bias + (gamma+1)
    gemm_bt_kernel<1><<<dim3(8, 32), 256, 0, stream>>>(
        attn, woT, 4096, 1024, 1024, bo, gamma, nullptr, nullptr, nullptr, out);
}

// Round 5
// 194.961 us; speedup vs baseline: 1.1051x; 1.0743x over previous
//
#include <hip/hip_runtime.h>
#include <hip/hip_bf16.h>

// MultiHeadSelfAttention: B=2, S=2048, D=1024, H=16, DK=64
// R5: (a) attn: true LDS double-buffer, single barrier per k-tile (R4 was
//     latency-bound: both pipes <50%, write->sync->read serial chain).
//     (b) out GEMM: 64x128 tiles -> 512 blocks (was 256 = 1 block/CU).
//     (c) QKV GEMM: min 3 blocks/CU -> 768 blocks with no tail wave.

using bf16 = __hip_bfloat16;
typedef __attribute__((ext_vector_type(8))) short bf16x8;   // 8 bf16 = 4 VGPRs
typedef __attribute__((ext_vector_type(4))) short bf16x4;   // 4 bf16 = 2 VGPRs
typedef __attribute__((ext_vector_type(4))) float f32x4;

#define QSCALE 0.18033688011112042f   // (1/sqrt(64)) * log2(e)

static __device__ __forceinline__ f32x4 mfma_bf16(bf16x8 a, bf16x8 b, f32x4 c) {
    return __builtin_amdgcn_mfma_f32_16x16x32_bf16(a, b, c, 0, 0, 0);
}

// async global -> LDS, 16 bytes per lane (GEMM staging)
static __device__ __forceinline__ void gld_lds16(const void* g, void* s) {
    __builtin_amdgcn_global_load_lds(
        (const __attribute__((address_space(1))) unsigned int*)g,
        (__attribute__((address_space(3))) unsigned int*)s,
        16, 0, 0);
}

static __device__ __forceinline__ short f2s(float f) {
    bf16 h = __float2bfloat16(f);
    return *reinterpret_cast<short*>(&h);
}

// ---------------- cast x (fp32 -> bf16), vectorized ----------------
__global__ void cast_bf16_kernel(const float* __restrict__ in, bf16* __restrict__ out, int n4) {
    int i = blockIdx.x * blockDim.x + threadIdx.x;
    if (i >= n4) return;
    float4 f = reinterpret_cast<const float4*>(in)[i];
    out[4*i+0] = __float2bfloat16(f.x);
    out[4*i+1] = __float2bfloat16(f.y);
    out[4*i+2] = __float2bfloat16(f.z);
    out[4*i+3] = __float2bfloat16(f.w);
}

// ---------------- transpose + cast: in fp32 [R][C] -> out bf16 [C][R] ----------------
__global__ void transpose_cast_kernel(const float* __restrict__ in, bf16* __restrict__ out,
                                      int R, int C) {
    __shared__ float tile[32][33];
    int c0 = blockIdx.x * 32, r0 = blockIdx.y * 32;
    int x = threadIdx.x, y = threadIdx.y;   // block (32,8)
#pragma unroll
    for (int i = 0; i < 32; i += 8) tile[y + i][x] = in[(size_t)(r0 + y + i) * C + c0 + x];
    __syncthreads();
#pragma unroll
    for (int i = 0; i < 32; i += 8)
        out[(size_t)(c0 + y + i) * R + r0 + x] = __float2bfloat16(tile[x][y + i]);
}

// ---------------- transpose V: [bh][2048][64] -> [bh][64][2048] (bf16) ----------------
__global__ void transpose_v_kernel(const bf16* __restrict__ in, bf16* __restrict__ out) {
    __shared__ bf16 t[64][72];
    const int bh = blockIdx.y, s0 = blockIdx.x * 64;
    const int r = threadIdx.x >> 2, c16 = (threadIdx.x & 3) * 16;
    const uint4* src = (const uint4*)(in + ((size_t)bh * 2048 + s0 + r) * 64 + c16);
    uint4 a = src[0], b = src[1];
    *(uint4*)&t[r][c16] = a;
    *(uint4*)&t[r][c16 + 8] = b;
    __syncthreads();
    bf16 tmp[16];
#pragma unroll
    for (int i = 0; i < 16; ++i) tmp[i] = t[c16 + i][r];
    uint4* dst = (uint4*)(out + ((size_t)bh * 64 + r) * 2048 + s0 + c16);
    dst[0] = ((uint4*)tmp)[0];
    dst[1] = ((uint4*)tmp)[1];
}

// ---------------- GEMM: C[M,N] = A[M,K] @ Bt[N,K]^T  (bf16 in, fp32 acc) ----------------
// TM x 128 block tile, BK=64, 4 waves in 2x2; wave tile (TM/2) x 64.
template <int EPI, int TM, int MINW>
__global__ __launch_bounds__(256, MINW)
void gemm_bt_kernel(const bf16* __restrict__ A, const bf16* __restrict__ Bt,
                    int M, int N, int K,
                    const float* __restrict__ bias, const float* __restrict__ gamma,
                    bf16* __restrict__ Qout, bf16* __restrict__ Kout, bf16* __restrict__ Vout,
                    float* __restrict__ Cout) {
    constexpr int MI = TM / 32;   // mfma m-tiles per wave
    constexpr int CA = TM / 32;   // 16B staging rounds per thread for A
    __shared__ __align__(16) bf16 As[TM * 64];
    __shared__ __align__(16) bf16 Bs[128 * 64];

    const int tid  = threadIdx.x;
    const int wave = tid >> 6, lane = tid & 63;
    const int quad = lane >> 4, l16 = lane & 15;
    const int wr = wave >> 1, wc = wave & 1;
    const int bm = blockIdx.y, bn = blockIdx.x;

    f32x4 acc[MI][4] = {};

    const int crow = lane >> 3;
    const int sblk = (lane & 7) ^ (crow & 7);
    const bf16* gA[CA]; const bf16* gB[4]; bf16* lA[CA]; bf16* lB[4];
#pragma unroll
    for (int c = 0; c < CA; ++c) {
        int ch = wave * CA + c;
        gA[c] = A + (size_t)(bm * TM + ch * 8 + crow) * K + sblk * 8;
        lA[c] = As + ch * 512 + lane * 8;
    }
#pragma unroll
    for (int c = 0; c < 4; ++c) {
        int ch = wave * 4 + c;
        gB[c] = Bt + (size_t)(bn * 128 + ch * 8 + crow) * K + sblk * 8;
        lB[c] = Bs + ch * 512 + lane * 8;
    }
    const int xr = l16 & 7;

    for (int k0 = 0; k0 < K; k0 += 64) {
#pragma unroll
        for (int c = 0; c < CA; ++c) gld_lds16(gA[c] + k0, lA[c]);
#pragma unroll
        for (int c = 0; c < 4; ++c) gld_lds16(gB[c] + k0, lB[c]);
        __syncthreads();
#pragma unroll
        for (int ks = 0; ks < 2; ++ks) {
            bf16x8 af[MI], bfr[4];
#pragma unroll
            for (int mi = 0; mi < MI; ++mi)
                af[mi] = *(const bf16x8*)(As + (wr * (TM/2) + mi * 16 + l16) * 64 + ((4 * ks + quad) ^ xr) * 8);
#pragma unroll
            for (int ni = 0; ni < 4; ++ni)
                bfr[ni] = *(const bf16x8*)(Bs + (wc * 64 + ni * 16 + l16) * 64 + ((4 * ks + quad) ^ xr) * 8);
#pragma unroll
            for (int mi = 0; mi < MI; ++mi)
#pragma unroll
                for (int ni = 0; ni < 4; ++ni)
                    acc[mi][ni] = mfma_bf16(af[mi], bfr[ni], acc[mi][ni]);
        }
        __syncthreads();
    }

#pragma unroll
    for (int mi = 0; mi < MI; ++mi) {
#pragma unroll
        for (int ni = 0; ni < 4; ++ni) {
#pragma unroll
            for (int r = 0; r < 4; ++r) {
                int row = bm * TM + wr * (TM/2) + mi * 16 + quad * 4 + r;
                int col = bn * 128 + wc * 64 + ni * 16 + l16;
                float v = acc[mi][ni][r];
                if (EPI == 0) {
                    v += bias[col];
                    int h = col / 192;
                    int rr = col - h * 192;
                    int which = rr >> 6, dk = rr & 63;
                    int b = row >> 11, s = row & 2047;   // S = 2048
                    size_t bh = (size_t)b * 16 + h;
                    if (which == 0) {
                        Qout[(bh * 2048 + s) * 64 + dk] = __float2bfloat16(v * QSCALE);
                    } else if (which == 1) {
                        Kout[(bh * 2048 + s) * 64 + dk] = __float2bfloat16(v);
                    } else {
                        Vout[(bh * 2048 + s) * 64 + dk] = __float2bfloat16(v);
                    }
                } else {
                    float o = (gamma[col] + 1.0f) * (v + bias[col]);
                    Cout[(size_t)row * N + col] = o;
                }
            }
        }
    }
}

// ---------------- flash attention, S^T orientation, LDS double-buffer ----------------
// grid: (S/128, B*H). block 256 = 4 waves; wave w owns q rows [q0+32w, q0+32w+32).
// One barrier per k-tile: at iter top write tile kt+1 (regs from last iter) into
// buf[nxt], prefetch tile kt+2 into regs, compute from buf[cur].
__global__ __launch_bounds__(256, 2)
void attn_kernel(const bf16* __restrict__ Qb, const bf16* __restrict__ Kb,
                 const bf16* __restrict__ Vt, const int* __restrict__ mask,
                 bf16* __restrict__ Aout) {
    __shared__ __align__(16) bf16 Ks[2][64 * 72];   // K tile [kpos][dk]
    __shared__ __align__(16) bf16 Vs[2][64 * 76];   // V^T tile [dk][kpos]
    __shared__ __align__(16) float Biass[2][64];

    const int bh = blockIdx.y;
    const int b = bh >> 4, h = bh & 15;
    const int q0 = blockIdx.x * 128;
    const int tid = threadIdx.x;
    const int wave = tid >> 6, lane = tid & 63;
    const int quad = lane >> 4, l16 = lane & 15;

    // Q fragments (B-operand of S^T MFMA)
    bf16x8 aq[2][2];
#pragma unroll
    for (int m = 0; m < 2; ++m) {
        const bf16* qp = Qb + ((size_t)bh * 2048 + q0 + wave * 32 + m * 16 + l16) * 64;
        aq[m][0] = *(const bf16x8*)(qp + quad * 8);
        aq[m][1] = *(const bf16x8*)(qp + 32 + quad * 8);
    }

    bf16x8 ones;
#pragma unroll
    for (int j = 0; j < 8; ++j) ones[j] = (short)0x3F80;   // bf16 1.0

    f32x4 O[2][4] = {};
    f32x4 Lacc[2] = {};

    // staging: thread t -> row t>>2 (0..63), part t&3 -> 16 bf16 = 2x uint4
    const int srow = tid >> 2, spart = tid & 3;
    const bf16* gK = Kb + ((size_t)bh * 2048 + srow) * 64 + spart * 16;
    const bf16* gV = Vt + ((size_t)bh * 64 + srow) * 2048 + spart * 16;
    uint4* lK[2]; uint4* lV[2];
#pragma unroll
    for (int p = 0; p < 2; ++p) {
        lK[p] = (uint4*)(Ks[p] + srow * 72 + spart * 16);
        lV[p] = (uint4*)(Vs[p] + srow * 76 + spart * 16);
    }

    // prologue: tile 0 -> regs -> buf0 ; tile 1 -> regs
    uint4 kr0, kr1, vr0, vr1; int mreg = 1;
    {
        const uint4* nk = (const uint4*)gK;
        const uint4* nv = (const uint4*)gV;
        kr0 = nk[0]; kr1 = nk[1]; vr0 = nv[0]; vr1 = nv[1];
        if (tid < 64) mreg = mask[b * 2048 + tid];
        lK[0][0] = kr0; lK[0][1] = kr1;
        lV[0][0] = vr0; lV[0][1] = vr1;
        if (tid < 64) Biass[0][tid] = mreg ? -24.0f : -1e30f;
        const uint4* nk1 = (const uint4*)(gK + 4096);
        const uint4* nv1 = (const uint4*)(gV + 64);
        kr0 = nk1[0]; kr1 = nk1[1]; vr0 = nv1[0]; vr1 = nv1[1];
        if (tid < 64) mreg = mask[b * 2048 + 64 + tid];
    }

    for (int kt = 0; kt < 32; ++kt) {
        __syncthreads();   // buf[cur] ready; all reads of buf[nxt] (iter kt-1) done
        const int cur = kt & 1, nxt = cur ^ 1;

        if (kt + 1 < 32) {   // write tile kt+1 (regs loaded last iter; vmcnt drained)
            lK[nxt][0] = kr0; lK[nxt][1] = kr1;
            lV[nxt][0] = vr0; lV[nxt][1] = vr1;
            if (tid < 64) Biass[nxt][tid] = mreg ? -24.0f : -1e30f;
        }
        if (kt + 2 < 32) {   // prefetch tile kt+2 into regs (hidden by compute)
            const uint4* nk = (const uint4*)(gK + (size_t)(kt + 2) * 4096);
            const uint4* nv = (const uint4*)(gV + (kt + 2) * 64);
            kr0 = nk[0]; kr1 = nk[1]; vr0 = nv[0]; vr1 = nv[1];
            if (tid < 64) mreg = mask[b * 2048 + (kt + 2) * 64 + tid];
        }

        // hoisted: bias rows, K A-frags, V B-frags
        f32x4 bias4[4];
        bf16x8 bk[4][2];
#pragma unroll
        for (int kt4 = 0; kt4 < 4; ++kt4) {
            bias4[kt4] = *(const f32x4*)(&Biass[cur][0] + kt4 * 16 + quad * 4);
            const bf16* kp = Ks[cur] + (kt4 * 16 + l16) * 72 + quad * 8;
            bk[kt4][0] = *(const bf16x8*)kp;
            bk[kt4][1] = *(const bf16x8*)(kp + 32);
        }
        bf16x8 bv8[2][4];
#pragma unroll
        for (int a = 0; a < 2; ++a) {
#pragma unroll
            for (int nt = 0; nt < 4; ++nt) {
                const bf16* vp = Vs[cur] + (nt * 16 + l16) * 76 + a * 32 + quad * 4;
                bf16x4 lo = *(const bf16x4*)vp;          // kpos 32a+4q+0..3   (j=0..3)
                bf16x4 hi = *(const bf16x4*)(vp + 16);   // kpos 32a+16+4q+0..3 (j=4..7)
                bf16x8 f;
                f[0] = lo[0]; f[1] = lo[1]; f[2] = lo[2]; f[3] = lo[3];
                f[4] = hi[0]; f[5] = hi[1]; f[6] = hi[2]; f[7] = hi[3];
                bv8[a][nt] = f;
            }
        }

#pragma unroll
        for (int m = 0; m < 2; ++m) {
            f32x4 sv[4];
#pragma unroll
            for (int kt4 = 0; kt4 < 4; ++kt4) {
                f32x4 c = {0.f, 0.f, 0.f, 0.f};
                c = mfma_bf16(bk[kt4][0], aq[m][0], c);
                c = mfma_bf16(bk[kt4][1], aq[m][1], c);
                sv[kt4] = c;
            }
            float p[4][4];
#pragma unroll
            for (int kt4 = 0; kt4 < 4; ++kt4)
#pragma unroll
                for (int r = 0; r < 4; ++r)
                    p[kt4][r] = __builtin_amdgcn_exp2f(sv[kt4][r] + bias4[kt4][r]);

#pragma unroll
            for (int a = 0; a < 2; ++a) {
                bf16x8 pa;
                pa[0] = f2s(p[2*a][0]);   pa[1] = f2s(p[2*a][1]);
                pa[2] = f2s(p[2*a][2]);   pa[3] = f2s(p[2*a][3]);
                pa[4] = f2s(p[2*a+1][0]); pa[5] = f2s(p[2*a+1][1]);
                pa[6] = f2s(p[2*a+1][2]); pa[7] = f2s(p[2*a+1][3]);
                Lacc[m] = mfma_bf16(pa, ones, Lacc[m]);
#pragma unroll
                for (int nt = 0; nt < 4; ++nt)
                    O[m][nt] = mfma_bf16(pa, bv8[a][nt], O[m][nt]);
            }
        }
    }

    // epilogue: O / l
#pragma unroll
    for (int m = 0; m < 2; ++m) {
        float inv[4];
#pragma unroll
        for (int r = 0; r < 4; ++r) inv[r] = __builtin_amdgcn_rcpf(Lacc[m][r]);
#pragma unroll
        for (int nt = 0; nt < 4; ++nt) {
#pragma unroll
            for (int r = 0; r < 4; ++r) {
                int row = q0 + wave * 32 + m * 16 + quad * 4 + r;
                Aout[((size_t)b * 2048 + row) * 1024 + h * 64 + nt * 16 + l16] =
                    __float2bfloat16(O[m][nt][r] * inv[r]);
            }
        }
    }
}

// ---------------- launcher ----------------
extern "C" void kernel_launch(void* const* d_in, const int* in_sizes, int n_in,
                              void* d_out, int out_size, void* d_ws, size_t ws_size,
                              hipStream_t stream) {
    const float* x     = (const float*)d_in[0];
    const float* gamma = (const float*)d_in[1];
    const int*   mask  = (const int*)d_in[2];
    const float* wqkv  = (const float*)d_in[3];
    const float* bqkv  = (const float*)d_in[4];
    const float* wo    = (const float*)d_in[5];
    const float* bo    = (const float*)d_in[6];
    float* out = (float*)d_out;

    char* ws = (char*)d_ws;
    const size_t MB = 1u << 20;
    bf16* xb    = (bf16*)(ws);            //  8 MB: x cast to bf16      [4096][1024]
    bf16* wqkvT = (bf16*)(ws + 8 * MB);   //  6 MB: W_qkv^T bf16        [3072][1024]
    bf16* woT   = (bf16*)(ws + 14 * MB);  //  2 MB: W_o^T bf16          [1024][1024]
    bf16* Qb    = (bf16*)(ws + 16 * MB);  //  8 MB: Q per head (scaled) [bh][s][dk]
    bf16* Kb    = (bf16*)(ws + 24 * MB);  //  8 MB: K per head          [bh][s][dk]
    bf16* Vt    = (bf16*)(ws + 32 * MB);  //  8 MB: V^T per head        [bh][dk][s]
    bf16* Vtmp  = (bf16*)(ws + 40 * MB);  //  8 MB: V coalesced (dead after transpose)
    bf16* attn  = (bf16*)(ws + 40 * MB);  //  8 MB: attention out (reuses Vtmp slot)

    cast_bf16_kernel<<<4096, 256, 0, stream>>>(x, xb, 4194304 / 4);
    transpose_cast_kernel<<<dim3(96, 32), dim3(32, 8), 0, stream>>>(wqkv, wqkvT, 1024, 3072);
    transpose_cast_kernel<<<dim3(32, 32), dim3(32, 8), 0, stream>>>(wo, woT, 1024, 1024);

    // QKV GEMM: [4096,1024] x [1024,3072], 768 blocks = 3/CU exactly
    gemm_bt_kernel<0, 128, 3><<<dim3(24, 32), 256, 0, stream>>>(
        xb, wqkvT, 4096, 3072, 1024, bqkv, nullptr, Qb, Kb, Vtmp, nullptr);

    // V transpose: [bh][s][dk] -> [bh][dk][s]
    transpose_v_kernel<<<dim3(32, 32), 256, 0, stream>>>(Vtmp, Vt);

    // attention: grid (S/128, B*H)
    attn_kernel<<<dim3(16, 32), 256, 0, stream>>>(Qb, Kb, Vt, mask, attn);

    // out GEMM: [4096,1024] x [1024,1024], 64x128 tiles -> 512 blocks
    gemm_bt_kernel<1, 64, 4><<<dim3(8, 64), 256, 0, stream>>>(
        attn, woT, 4096, 1024, 1024, bo, gamma, nullptr, nullptr, nullptr, out);
}

// Round 6
// 188.842 us; speedup vs baseline: 1.1409x; 1.0324x over previous
//
#include <hip/hip_runtime.h>
#include <hip/hip_bf16.h>

// MultiHeadSelfAttention: B=2, S=2048, D=1024, H=16, DK=64
// R6: attn rebuilt for LDS-traffic scaling: 2 waves/block x 64 q-rows/wave
//     (frag reads amortized over 4x the MFMA work), gld_lds16 double-buffered
//     K/V staging (DMA k+1 issued before compute k), XOR-swizzled stride-64 LDS,
//     V^T pre-permuted so PV B-frags are single b128 reads. Prep kernels fused.

using bf16 = __hip_bfloat16;
typedef __attribute__((ext_vector_type(8))) short bf16x8;   // 8 bf16 = 4 VGPRs
typedef __attribute__((ext_vector_type(4))) float f32x4;

#define QSCALE 0.18033688011112042f   // (1/sqrt(64)) * log2(e)

static __device__ __forceinline__ f32x4 mfma_bf16(bf16x8 a, bf16x8 b, f32x4 c) {
    return __builtin_amdgcn_mfma_f32_16x16x32_bf16(a, b, c, 0, 0, 0);
}

static __device__ __forceinline__ void gld_lds16(const void* g, void* s) {
    __builtin_amdgcn_global_load_lds(
        (const __attribute__((address_space(1))) unsigned int*)g,
        (__attribute__((address_space(3))) unsigned int*)s,
        16, 0, 0);
}

static __device__ __forceinline__ short f2s(float f) {
    bf16 h = __float2bfloat16(f);
    return *reinterpret_cast<short*>(&h);
}

// ---------------- fused prep: cast x + transpose both weights ----------------
// blocks [0,4096): cast x (fp32->bf16, 1M float4)
// blocks [4096,7168): transpose wqkv [1024][3072] -> [3072][1024]
// blocks [7168,8192): transpose wo   [1024][1024] -> [1024][1024]^T
__global__ void prep_kernel(const float* __restrict__ x, bf16* __restrict__ xb,
                            const float* __restrict__ wqkv, bf16* __restrict__ wqkvT,
                            const float* __restrict__ wo, bf16* __restrict__ woT) {
    __shared__ float tile[32][33];
    int blk = blockIdx.x;
    if (blk < 4096) {
        int i = blk * 256 + threadIdx.x;
        float4 f = reinterpret_cast<const float4*>(x)[i];
        xb[4*i+0] = __float2bfloat16(f.x);
        xb[4*i+1] = __float2bfloat16(f.y);
        xb[4*i+2] = __float2bfloat16(f.z);
        xb[4*i+3] = __float2bfloat16(f.w);
        return;
    }
    const float* in; bf16* out; int R, C, bx, by;
    if (blk < 7168) {
        int idx = blk - 4096; in = wqkv; out = wqkvT; R = 1024; C = 3072;
        bx = idx % 96; by = idx / 96;
    } else {
        int idx = blk - 7168; in = wo; out = woT; R = 1024; C = 1024;
        bx = idx & 31; by = idx >> 5;
    }
    int c0 = bx * 32, r0 = by * 32;
    int xo = threadIdx.x & 31, yo = threadIdx.x >> 5;   // (32,8)
#pragma unroll
    for (int i = 0; i < 32; i += 8) tile[yo + i][xo] = in[(size_t)(r0 + yo + i) * C + c0 + xo];
    __syncthreads();
#pragma unroll
    for (int i = 0; i < 32; i += 8)
        out[(size_t)(c0 + yo + i) * R + r0 + xo] = __float2bfloat16(tile[xo][yo + i]);
}

// ---------------- transpose V + dual-slice kpos permutation ----------------
// in [bh][2048][64] -> out [bh][64][2048], where within each 64-kpos chunk,
// position a*32+q*8+jj holds original kpos a*32+q*4+jj (jj<4) / a*32+16+q*4+jj-4.
// This makes each attn PV B-frag one aligned 16B read.
__global__ void transpose_v_kernel(const bf16* __restrict__ in, bf16* __restrict__ out) {
    __shared__ bf16 t[64][72];
    const int bh = blockIdx.y, s0 = blockIdx.x * 64;
    const int r = threadIdx.x >> 2, c16 = (threadIdx.x & 3) * 16;
    const uint4* src = (const uint4*)(in + ((size_t)bh * 2048 + s0 + r) * 64 + c16);
    uint4 a0 = src[0], a1 = src[1];
    *(uint4*)&t[r][c16] = a0;
    *(uint4*)&t[r][c16 + 8] = a1;
    __syncthreads();
    bf16 tmp[16];
#pragma unroll
    for (int ii = 0; ii < 16; ++ii) {
        int i = c16 + ii;
        int a = i >> 5, rem = i & 31, q = rem >> 3, jj = rem & 7;
        int sp = a * 32 + q * 4 + (jj < 4 ? jj : 16 + jj - 4);
        tmp[ii] = t[sp][r];
    }
    uint4* dst = (uint4*)(out + ((size_t)bh * 64 + r) * 2048 + s0 + c16);
    dst[0] = ((uint4*)tmp)[0];
    dst[1] = ((uint4*)tmp)[1];
}

// ---------------- GEMM: C[M,N] = A[M,K] @ Bt[N,K]^T  (bf16 in, fp32 acc) ----------------
template <int EPI, int TM, int MINW>
__global__ __launch_bounds__(256, MINW)
void gemm_bt_kernel(const bf16* __restrict__ A, const bf16* __restrict__ Bt,
                    int M, int N, int K,
                    const float* __restrict__ bias, const float* __restrict__ gamma,
                    bf16* __restrict__ Qout, bf16* __restrict__ Kout, bf16* __restrict__ Vout,
                    float* __restrict__ Cout) {
    constexpr int MI = TM / 32;
    constexpr int CA = TM / 32;
    __shared__ __align__(16) bf16 As[TM * 64];
    __shared__ __align__(16) bf16 Bs[128 * 64];

    const int tid  = threadIdx.x;
    const int wave = tid >> 6, lane = tid & 63;
    const int quad = lane >> 4, l16 = lane & 15;
    const int wr = wave >> 1, wc = wave & 1;
    const int bm = blockIdx.y, bn = blockIdx.x;

    f32x4 acc[MI][4] = {};

    const int crow = lane >> 3;
    const int sblk = (lane & 7) ^ (crow & 7);
    const bf16* gA[CA]; const bf16* gB[4]; bf16* lA[CA]; bf16* lB[4];
#pragma unroll
    for (int c = 0; c < CA; ++c) {
        int ch = wave * CA + c;
        gA[c] = A + (size_t)(bm * TM + ch * 8 + crow) * K + sblk * 8;
        lA[c] = As + ch * 512 + lane * 8;
    }
#pragma unroll
    for (int c = 0; c < 4; ++c) {
        int ch = wave * 4 + c;
        gB[c] = Bt + (size_t)(bn * 128 + ch * 8 + crow) * K + sblk * 8;
        lB[c] = Bs + ch * 512 + lane * 8;
    }
    const int xr = l16 & 7;

    for (int k0 = 0; k0 < K; k0 += 64) {
#pragma unroll
        for (int c = 0; c < CA; ++c) gld_lds16(gA[c] + k0, lA[c]);
#pragma unroll
        for (int c = 0; c < 4; ++c) gld_lds16(gB[c] + k0, lB[c]);
        __syncthreads();
#pragma unroll
        for (int ks = 0; ks < 2; ++ks) {
            bf16x8 af[MI], bfr[4];
#pragma unroll
            for (int mi = 0; mi < MI; ++mi)
                af[mi] = *(const bf16x8*)(As + (wr * (TM/2) + mi * 16 + l16) * 64 + ((4 * ks + quad) ^ xr) * 8);
#pragma unroll
            for (int ni = 0; ni < 4; ++ni)
                bfr[ni] = *(const bf16x8*)(Bs + (wc * 64 + ni * 16 + l16) * 64 + ((4 * ks + quad) ^ xr) * 8);
#pragma unroll
            for (int mi = 0; mi < MI; ++mi)
#pragma unroll
                for (int ni = 0; ni < 4; ++ni)
                    acc[mi][ni] = mfma_bf16(af[mi], bfr[ni], acc[mi][ni]);
        }
        __syncthreads();
    }

#pragma unroll
    for (int mi = 0; mi < MI; ++mi) {
#pragma unroll
        for (int ni = 0; ni < 4; ++ni) {
#pragma unroll
            for (int r = 0; r < 4; ++r) {
                int row = bm * TM + wr * (TM/2) + mi * 16 + quad * 4 + r;
                int col = bn * 128 + wc * 64 + ni * 16 + l16;
                float v = acc[mi][ni][r];
                if (EPI == 0) {
                    v += bias[col];
                    int h = col / 192;
                    int rr = col - h * 192;
                    int which = rr >> 6, dk = rr & 63;
                    int b = row >> 11, s = row & 2047;   // S = 2048
                    size_t bh = (size_t)b * 16 + h;
                    if (which == 0) {
                        Qout[(bh * 2048 + s) * 64 + dk] = __float2bfloat16(v * QSCALE);
                    } else if (which == 1) {
                        Kout[(bh * 2048 + s) * 64 + dk] = __float2bfloat16(v);
                    } else {
                        Vout[(bh * 2048 + s) * 64 + dk] = __float2bfloat16(v);
                    }
                } else {
                    float o = (gamma[col] + 1.0f) * (v + bias[col]);
                    Cout[(size_t)row * N + col] = o;
                }
            }
        }
    }
}

// ---------------- flash attention: 2 waves x 64 q-rows, DMA double-buffer ----------------
// grid (S/128, B*H), block 128. Wave w owns q rows [q0+64w, q0+64w+64) as m=0..3.
// S^T = K*Q^T orientation (R4); V^T pre-permuted so PV B-frag = 1 b128 read.
__global__ __launch_bounds__(128, 1)
void attn_kernel(const bf16* __restrict__ Qb, const bf16* __restrict__ Kb,
                 const bf16* __restrict__ Vtp, const int* __restrict__ mask,
                 bf16* __restrict__ Aout) {
    __shared__ __align__(16) bf16 Ks[2][64 * 64];   // [kpos][dk], XOR-swizzled 16B blocks
    __shared__ __align__(16) bf16 Vs[2][64 * 64];   // [dk][kpos-permuted], XOR-swizzled
    __shared__ float Biass[2][64];

    const int bh = blockIdx.y;
    const int b = bh >> 4, h = bh & 15;
    const int q0 = blockIdx.x * 128;
    const int tid = threadIdx.x;
    const int wave = tid >> 6, lane = tid & 63;
    const int quad = lane >> 4, l16 = lane & 15;
    const int xr = l16 & 7;

    // Q fragments: wave owns q rows q0 + wave*64 + m*16 + l16
    bf16x8 aq[4][2];
#pragma unroll
    for (int m = 0; m < 4; ++m) {
        const bf16* qp = Qb + ((size_t)bh * 2048 + q0 + wave * 64 + m * 16 + l16) * 64;
        aq[m][0] = *(const bf16x8*)(qp + quad * 8);
        aq[m][1] = *(const bf16x8*)(qp + 32 + quad * 8);
    }

    bf16x8 ones;
#pragma unroll
    for (int j = 0; j < 8; ++j) ones[j] = (short)0x3F80;   // bf16 1.0

    f32x4 O[4][4] = {};
    f32x4 Lacc[4] = {};

    // DMA staging: inst c stages rows [c*16 + wave*8, +8); lane l -> row +(l>>3),
    // phys 16B-block l&7 holds source block (l&7)^(l>>3).
    const int r8 = lane >> 3, b8 = lane & 7;
    const int srcb = b8 ^ r8;
    const bf16* gK = Kb  + ((size_t)bh * 2048 + wave * 8 + r8) * 64 + srcb * 8;
    const bf16* gV = Vtp + ((size_t)bh * 64 + wave * 8 + r8) * 2048 + srcb * 8;
    bf16* lK[2][4]; bf16* lV[2][4];
#pragma unroll
    for (int p = 0; p < 2; ++p)
#pragma unroll
        for (int c = 0; c < 4; ++c) {
            lK[p][c] = Ks[p] + c * 1024 + wave * 512 + lane * 8;
            lV[p][c] = Vs[p] + c * 1024 + wave * 512 + lane * 8;
        }

    // prologue: DMA tile 0 -> buf0; bias0; prefetch mask tile1
    int mreg = 0;
#pragma unroll
    for (int c = 0; c < 4; ++c) {
        gld_lds16(gK + c * 1024, lK[0][c]);
        gld_lds16(gV + (size_t)c * 32768, lV[0][c]);
    }
    if (tid < 64) {
        Biass[0][tid] = mask[b * 2048 + tid] ? -24.0f : -1e30f;
        mreg = mask[b * 2048 + 64 + tid];
    }

    for (int kt = 0; kt < 32; ++kt) {
        __syncthreads();   // buf[cur] DMA + bias landed; prior reads of buf[nxt] done
        const int cur = kt & 1, nxt = cur ^ 1;

        if (kt + 1 < 32) {
#pragma unroll
            for (int c = 0; c < 4; ++c) {
                gld_lds16(gK + (size_t)(kt + 1) * 4096 + c * 1024, lK[nxt][c]);
                gld_lds16(gV + (kt + 1) * 64 + (size_t)c * 32768, lV[nxt][c]);
            }
            if (tid < 64) Biass[nxt][tid] = mreg ? -24.0f : -1e30f;
        }
        if (kt + 2 < 32 && tid < 64) mreg = mask[b * 2048 + (kt + 2) * 64 + tid];

        // hoisted fragments (shared across all 4 m-groups)
        f32x4 bias4[4];
        bf16x8 bk[4][2];
#pragma unroll
        for (int kt4 = 0; kt4 < 4; ++kt4) {
            bias4[kt4] = *(const f32x4*)(&Biass[cur][0] + kt4 * 16 + quad * 4);
            const bf16* kp = Ks[cur] + (kt4 * 16 + l16) * 64;
            bk[kt4][0] = *(const bf16x8*)(kp + (quad ^ xr) * 8);
            bk[kt4][1] = *(const bf16x8*)(kp + ((quad + 4) ^ xr) * 8);
        }
        bf16x8 bv8[2][4];
#pragma unroll
        for (int a = 0; a < 2; ++a)
#pragma unroll
            for (int nt = 0; nt < 4; ++nt)
                bv8[a][nt] = *(const bf16x8*)(Vs[cur] + (nt * 16 + l16) * 64 + ((a * 4 + quad) ^ xr) * 8);

#pragma unroll
        for (int m = 0; m < 4; ++m) {
            f32x4 sv[4];
#pragma unroll
            for (int kt4 = 0; kt4 < 4; ++kt4) {
                f32x4 c = {0.f, 0.f, 0.f, 0.f};
                c = mfma_bf16(bk[kt4][0], aq[m][0], c);
                c = mfma_bf16(bk[kt4][1], aq[m][1], c);
                sv[kt4] = c;
            }
            float p[4][4];
#pragma unroll
            for (int kt4 = 0; kt4 < 4; ++kt4)
#pragma unroll
                for (int r = 0; r < 4; ++r)
                    p[kt4][r] = __builtin_amdgcn_exp2f(sv[kt4][r] + bias4[kt4][r]);

#pragma unroll
            for (int a = 0; a < 2; ++a) {
                bf16x8 pa;
                pa[0] = f2s(p[2*a][0]);   pa[1] = f2s(p[2*a][1]);
                pa[2] = f2s(p[2*a][2]);   pa[3] = f2s(p[2*a][3]);
                pa[4] = f2s(p[2*a+1][0]); pa[5] = f2s(p[2*a+1][1]);
                pa[6] = f2s(p[2*a+1][2]); pa[7] = f2s(p[2*a+1][3]);
                Lacc[m] = mfma_bf16(pa, ones, Lacc[m]);
#pragma unroll
                for (int nt = 0; nt < 4; ++nt)
                    O[m][nt] = mfma_bf16(pa, bv8[a][nt], O[m][nt]);
            }
        }
    }

    // epilogue: O / l
#pragma unroll
    for (int m = 0; m < 4; ++m) {
        float inv[4];
#pragma unroll
        for (int r = 0; r < 4; ++r) inv[r] = __builtin_amdgcn_rcpf(Lacc[m][r]);
#pragma unroll
        for (int nt = 0; nt < 4; ++nt) {
#pragma unroll
            for (int r = 0; r < 4; ++r) {
                int row = q0 + wave * 64 + m * 16 + quad * 4 + r;
                Aout[((size_t)b * 2048 + row) * 1024 + h * 64 + nt * 16 + l16] =
                    __float2bfloat16(O[m][nt][r] * inv[r]);
            }
        }
    }
}

// ---------------- launcher ----------------
extern "C" void kernel_launch(void* const* d_in, const int* in_sizes, int n_in,
                              void* d_out, int out_size, void* d_ws, size_t ws_size,
                              hipStream_t stream) {
    const float* x     = (const float*)d_in[0];
    const float* gamma = (const float*)d_in[1];
    const int*   mask  = (const int*)d_in[2];
    const float* wqkv  = (const float*)d_in[3];
    const float* bqkv  = (const float*)d_in[4];
    const float* wo    = (const float*)d_in[5];
    const float* bo    = (const float*)d_in[6];
    float* out = (float*)d_out;

    char* ws = (char*)d_ws;
    const size_t MB = 1u << 20;
    bf16* xb    = (bf16*)(ws);            //  8 MB: x cast to bf16      [4096][1024]
    bf16* wqkvT = (bf16*)(ws + 8 * MB);   //  6 MB: W_qkv^T bf16        [3072][1024]
    bf16* woT   = (bf16*)(ws + 14 * MB);  //  2 MB: W_o^T bf16          [1024][1024]
    bf16* Qb    = (bf16*)(ws + 16 * MB);  //  8 MB: Q per head (scaled) [bh][s][dk]
    bf16* Kb    = (bf16*)(ws + 24 * MB);  //  8 MB: K per head          [bh][s][dk]
    bf16* Vt    = (bf16*)(ws + 32 * MB);  //  8 MB: V^T permuted        [bh][dk][s']
    bf16* Vtmp  = (bf16*)(ws + 40 * MB);  //  8 MB: V coalesced (dead after transpose)
    bf16* attn  = (bf16*)(ws + 40 * MB);  //  8 MB: attention out (reuses Vtmp slot)

    prep_kernel<<<8192, 256, 0, stream>>>(x, xb, wqkv, wqkvT, wo, woT);

    // QKV GEMM: [4096,1024] x [1024,3072]
    gemm_bt_kernel<0, 128, 3><<<dim3(24, 32), 256, 0, stream>>>(
        xb, wqkvT, 4096, 3072, 1024, bqkv, nullptr, Qb, Kb, Vtmp, nullptr);

    // V transpose + kpos permutation
    transpose_v_kernel<<<dim3(32, 32), 256, 0, stream>>>(Vtmp, Vt);

    // attention: grid (S/128, B*H), 128-thread blocks
    attn_kernel<<<dim3(16, 32), 128, 0, stream>>>(Qb, Kb, Vt, mask, attn);

    // out GEMM: [4096,1024] x [1024,1024], fused bias + (gamma+1)
    gemm_bt_kernel<1, 64, 4><<<dim3(8, 64), 256, 0, stream>>>(
        attn, woT, 4096, 1024, 1024, bo, gamma, nullptr, nullptr, nullptr, out);
}